// Round 13
// baseline (240.039 us; speedup 1.0000x reference)
//
#include <hip/hip_runtime.h>
#include <math.h>

#define B_   16
#define C_   256
#define T_   8192
#define BINS 16
#define NFFT 30

typedef __attribute__((ext_vector_type(8))) _Float16 f16x8;
typedef __attribute__((ext_vector_type(2))) __fp16 fp16x2;
typedef __attribute__((ext_vector_type(4))) float f32x4;

typedef const __attribute__((address_space(1))) unsigned int ga_u32;
typedef __attribute__((address_space(3))) unsigned int ls_u32;

union f16pack { f16x8 v; fp16x2 p[4]; };

// ---------------- Kernel 1: k = Wk @ X  (fp16 out, float2 per thread) ----------------
__global__ __launch_bounds__(256) void k_kernel(const float* __restrict__ x,
                                                const float* __restrict__ Wk,
                                                _Float16* __restrict__ kk) {
  const int tc = blockIdx.x;   // 0..15
  const int b  = blockIdx.y;
  const int tid = threadIdx.x;
  const int t = tc*512 + tid*2;
  const float* xb = x + (size_t)b*C_*T_ + t;
  float2 acc[16];
#pragma unroll
  for (int cc = 0; cc < 16; ++cc) acc[cc] = make_float2(0.f, 0.f);
  for (int c4 = 0; c4 < 64; ++c4) {
    float2 xv[4];
#pragma unroll
    for (int j = 0; j < 4; ++j) xv[j] = *(const float2*)(xb + (size_t)(c4*4 + j)*T_);
#pragma unroll
    for (int cc = 0; cc < 16; ++cc) {
      const float4 w4 = *(const float4*)&Wk[cc*256 + c4*4];   // uniform -> s_load
      acc[cc].x += w4.x*xv[0].x + w4.y*xv[1].x + w4.z*xv[2].x + w4.w*xv[3].x;
      acc[cc].y += w4.x*xv[0].y + w4.y*xv[1].y + w4.z*xv[2].y + w4.w*xv[3].y;
    }
  }
#pragma unroll
  for (int cc = 0; cc < 16; ++cc) {
    fp16x2 hv;
    hv[0] = (__fp16)acc[cc].x;
    hv[1] = (__fp16)acc[cc].y;
    *(fp16x2*)&kk[((size_t)b*16 + cc)*T_ + t] = hv;
  }
}

// ---------------- Kernel 2: R partials = k @ X^T (MFMA, 32 K-splits) ----------------
static __device__ __forceinline__ void stage_panel(float* dstbase, const float* xb,
                                                   int koff, int tid) {
#pragma unroll
  for (int h = 0; h < 4; ++h) {
    const int idx = h*512 + tid;       // 0..2047 -> 2048 x 16B = 32 KB
    const int row = idx >> 3;          // 0..255
    const int ps  = idx & 7;           // physical 16B segment in row
    const int ls  = ps ^ (row & 7);    // logical segment (involution)
    const float* src = xb + (size_t)row*T_ + koff + ls*4;
    __builtin_amdgcn_global_load_lds((ga_u32*)src, (ls_u32*)(dstbase + idx*4), 16, 0, 0);
  }
}

__global__ __launch_bounds__(512, 4) void r_kernel(const float* __restrict__ x,
                                                   const _Float16* __restrict__ kk,
                                                   float* __restrict__ Rp) {
  const int ks = blockIdx.x;   // 0..31
  const int b  = blockIdx.y;
  constexpr int KCH = 256;

  __shared__ float P[2][256*32];

  const int tid  = threadIdx.x;
  const int lane = tid & 63;
  const int w    = tid >> 6;     // 0..7 -> ch-tile pair {2w, 2w+1}
  const int fr   = lane & 15;
  const int g    = lane >> 4;

  const float* xb = x + (size_t)b*C_*T_;
  const _Float16* kb = kk + (size_t)b*16*T_;
  const int t0 = ks * KCH;

  f32x4 acc[2];
  acc[0] = (f32x4){0.f,0.f,0.f,0.f};
  acc[1] = (f32x4){0.f,0.f,0.f,0.f};

  stage_panel(P[0], xb, t0, tid);
  __syncthreads();

  int cur = 0;
  for (int kt = 0; kt < KCH; kt += 32) {
    if (kt + 32 < KCH) stage_panel(P[cur ^ 1], xb, t0 + kt + 32, tid);

    const float* Pc = P[cur];
    const f16x8 ka = *(const f16x8*)&kb[(size_t)fr*T_ + t0 + kt + g*8];
#pragma unroll
    for (int nt = 0; nt < 2; ++nt) {
      const int r = (w*2 + nt)*16 + fr;   // ch row 0..255
      const float4 lo = *(const float4*)&Pc[r*32 + (((2*g+0) ^ (r&7))<<2)];
      const float4 hi = *(const float4*)&Pc[r*32 + (((2*g+1) ^ (r&7))<<2)];
      f16pack fb;
      fb.p[0] = __builtin_amdgcn_cvt_pkrtz(lo.x, lo.y);
      fb.p[1] = __builtin_amdgcn_cvt_pkrtz(lo.z, lo.w);
      fb.p[2] = __builtin_amdgcn_cvt_pkrtz(hi.x, hi.y);
      fb.p[3] = __builtin_amdgcn_cvt_pkrtz(hi.z, hi.w);
      acc[nt] = __builtin_amdgcn_mfma_f32_16x16x32_f16(ka, fb.v, acc[nt], 0, 0, 0);
    }
    __syncthreads();
    cur ^= 1;
  }

  float* rp = Rp + ((size_t)(ks*16 + b))*4096;
#pragma unroll
  for (int nt = 0; nt < 2; ++nt)
#pragma unroll
    for (int r = 0; r < 4; ++r) {
      const int cc = g*4 + r;               // C/D row = A-side m (cc)
      const int ch = (w*2 + nt)*16 + fr;    // C/D col = B-side n (ch)
      rp[cc*256 + ch] = acc[nt][r];
    }
}

// ---------------- Kernel 2b: parallel reduce of 32 Rp partials -> wkg ----------------
__global__ __launch_bounds__(256) void reduce_kernel(const float* __restrict__ Rp,
                                                     float* __restrict__ wkg) {
  const int idx = blockIdx.x*256 + threadIdx.x;   // 0..65535
  const int b   = idx >> 12;
  const int rem = idx & 4095;
  float s = 0.f;
#pragma unroll 8
  for (int p = 0; p < 32; ++p)
    s += Rp[((size_t)(p*16 + b))*4096 + rem];
  wkg[idx] = s;
}

// ---------------- Kernel 3: scores -> softmax -> M = P @ Wv (512 thr) ----------------
__global__ __launch_bounds__(512) void attn_b(const float* __restrict__ Wq,
                                              const float* __restrict__ Wv,
                                              const float* __restrict__ wkg,
                                              float* __restrict__ Mout) {
  const int b = blockIdx.x;
  const int tid = threadIdx.x;
  __shared__ float s1[16*256];
  __shared__ float s2[16*256];
  __shared__ float invs[16];

  for (int i = tid; i < 4096; i += 512) s1[i] = wkg[(size_t)b*4096 + i];
  __syncthreads();

  const int h   = tid >> 8;    // 0..1 (cc half)
  const int col = tid & 255;

  float sc[8];
#pragma unroll
  for (int i = 0; i < 8; ++i) sc[i] = 0.f;
  for (int c4 = 0; c4 < 64; ++c4) {
    const float4 wq4 = *(const float4*)&Wq[(size_t)col*256 + c4*4];
#pragma unroll
    for (int i = 0; i < 8; ++i) {
      const float4 p4 = *(const float4*)&s1[(h*8 + i)*256 + c4*4];
      sc[i] += p4.x*wq4.x + p4.y*wq4.y + p4.z*wq4.z + p4.w*wq4.w;
    }
  }
#pragma unroll
  for (int i = 0; i < 8; ++i) s2[(h*8 + i)*256 + col] = sc[i] * 0.0625f;
  __syncthreads();

  {
    const int rr = tid >> 5, jj = tid & 31;
    float mx = -1e30f;
    for (int c = jj; c < 256; c += 32) mx = fmaxf(mx, s2[rr*256 + c]);
#pragma unroll
    for (int o = 1; o < 32; o <<= 1) mx = fmaxf(mx, __shfl_xor(mx, o, 64));
    float sm = 0.f;
    for (int c = jj; c < 256; c += 32) {
      const float e = __expf(s2[rr*256 + c] - mx);
      s2[rr*256 + c] = e;
      sm += e;
    }
#pragma unroll
    for (int o = 1; o < 32; o <<= 1) sm += __shfl_xor(sm, o, 64);
    if (jj == 0) invs[rr] = 1.f / sm;
  }
  __syncthreads();

  float mac[8];
#pragma unroll
  for (int i = 0; i < 8; ++i) mac[i] = 0.f;
  for (int c4 = 0; c4 < 64; ++c4) {
    float wv[4];
#pragma unroll
    for (int j = 0; j < 4; ++j) wv[j] = Wv[(size_t)(c4*4 + j)*256 + col];
#pragma unroll
    for (int i = 0; i < 8; ++i) {
      const float4 p4 = *(const float4*)&s2[(h*8 + i)*256 + c4*4];
      mac[i] += p4.x*wv[0] + p4.y*wv[1] + p4.z*wv[2] + p4.w*wv[3];
    }
  }
#pragma unroll
  for (int i = 0; i < 8; ++i)
    Mout[(size_t)b*4096 + (h*8 + i)*256 + col] = mac[i] * invs[h*8 + i];
}

// ---------------- Kernel 4: fused  seq-window = M @ X  ->  DFT power ----------------
// Grid (32 tcx, 16 b, 2 cc-half), 256 thr. Computes 8 seq rows over the
// 288-sample window locally (x from L3, M in LDS transposed), then the
// spectrogram for those rows. No global seq buffer.
#define SLP 292   // 288 + 4 pad (bank rotate, keeps 16B align)

__global__ __launch_bounds__(256) void outspec(const float* __restrict__ x,
                                               const float* __restrict__ M,
                                               float* __restrict__ out) {
  const int tcx = blockIdx.x;  // 0..31
  const int b   = blockIdx.y;  // 0..15
  const int hf  = blockIdx.z;  // 0..1
  const int tid = threadIdx.x;
  const int t0  = tcx * 256;

  __shared__ float Mt[256*8];      // Mt[ch][c'] for cc = hf*8+c'
  __shared__ float sl[8*SLP];      // seq rows (window)
  __shared__ float ctab[BINS*NFFT];
  __shared__ float stab[BINS*NFFT];

  for (int i = tid; i < 2048; i += 256) {
    const int ch = i >> 3, c = i & 7;
    Mt[ch*8 + c] = M[(size_t)b*4096 + (hf*8 + c)*256 + ch];
  }
  for (int i = tid; i < BINS*NFFT; i += 256) {
    const int k = i / NFFT, n = i % NFFT;
    const float TWO_PI = 6.283185307179586f;
    const float wn = 0.5f - 0.5f * cosf(TWO_PI * (float)n / (float)NFFT);
    const float ang = TWO_PI * (float)(k * n) / (float)NFFT;
    ctab[i] = cosf(ang) * wn;
    stab[i] = sinf(ang) * wn;
  }
  __syncthreads();

  // ---- seq window: i = tid (+256 for tid<32) ----
  const float* xb = x + (size_t)b*C_*T_;
#pragma unroll
  for (int pass = 0; pass < 2; ++pass) {
    const int i = pass*256 + tid;
    if (i < 288) {
      int t = t0 - 15 + i;
      if (t < 0) t = -t;
      if (t > T_-1) t = 2*(T_-1) - t;
      float acc[8];
#pragma unroll
      for (int c = 0; c < 8; ++c) acc[c] = 0.f;
      for (int c4 = 0; c4 < 64; ++c4) {
        float xv[4];
#pragma unroll
        for (int j = 0; j < 4; ++j) xv[j] = xb[(size_t)(c4*4 + j)*T_ + t];
#pragma unroll
        for (int j = 0; j < 4; ++j) {
          const float4 m0 = *(const float4*)&Mt[(c4*4 + j)*8];
          const float4 m1 = *(const float4*)&Mt[(c4*4 + j)*8 + 4];
          acc[0] += xv[j]*m0.x; acc[1] += xv[j]*m0.y;
          acc[2] += xv[j]*m0.z; acc[3] += xv[j]*m0.w;
          acc[4] += xv[j]*m1.x; acc[5] += xv[j]*m1.y;
          acc[6] += xv[j]*m1.z; acc[7] += xv[j]*m1.w;
        }
      }
#pragma unroll
      for (int c = 0; c < 8; ++c) sl[c*SLP + i] = acc[c];
    }
  }
  __syncthreads();

  // ---- spectrogram for the 8 rows ----
  const int k   = tid >> 4;
  const int sub = tid & 15;
  float cr[NFFT], ci[NFFT];
#pragma unroll
  for (int n = 0; n < NFFT; ++n) { cr[n] = ctab[k*NFFT + n]; ci[n] = stab[k*NFFT + n]; }

  const float inv_norm = 1.0f / 11.25f;
  for (int c = 0; c < 8; ++c) {
    const float* row = &sl[c*SLP];
    float* orow = out + (((size_t)(b*16 + hf*8 + c))*BINS + k)*T_ + t0;
#pragma unroll
    for (int jj = 0; jj < 4; ++jj) {
      const int x0 = 4*sub + 64*jj;
      float smp[36];
#pragma unroll
      for (int q = 0; q < 9; ++q) {
        const float4 v = *(const float4*)&row[x0 + 4*q];
        smp[4*q+0] = v.x; smp[4*q+1] = v.y; smp[4*q+2] = v.z; smp[4*q+3] = v.w;
      }
      float4 pw;
#pragma unroll
      for (int p = 0; p < 4; ++p) {
        float re = 0.f, im = 0.f;
#pragma unroll
        for (int n = 0; n < NFFT; ++n) {
          re += cr[n] * smp[p + n];
          im += ci[n] * smp[p + n];
        }
        ((float*)&pw)[p] = (re*re + im*im) * inv_norm;
      }
      *(float4*)(orow + x0) = pw;
    }
  }
}

// ---------------- launch ----------------
extern "C" void kernel_launch(void* const* d_in, const int* in_sizes, int n_in,
                              void* d_out, int out_size, void* d_ws, size_t ws_size,
                              hipStream_t stream) {
  const float* x  = (const float*)d_in[0];
  const float* Wk = (const float*)d_in[1];
  const float* Wq = (const float*)d_in[2];
  const float* Wv = (const float*)d_in[3];
  float* out = (float*)d_out;
  float* ws  = (float*)d_ws;

  // float-slot layout (~13 MB):
  _Float16* kk = (_Float16*)ws;            // 16*16*8192 halfs = 1,048,576 slots
  float* Rp   = ws + 1048576;              // 32*16*16*256 = 2,097,152
  float* wkg  = Rp + 2097152;              // 65,536
  float* M    = wkg + 65536;               // 65,536

  k_kernel<<<dim3(16, 16), 256, 0, stream>>>(x, Wk, kk);
  r_kernel<<<dim3(32, 16), 512, 0, stream>>>(x, kk, Rp);
  reduce_kernel<<<dim3(256), 256, 0, stream>>>(Rp, wkg);
  attn_b<<<dim3(16), 512, 0, stream>>>(Wq, Wv, wkg, M);
  outspec<<<dim3(32, 16, 2), 256, 0, stream>>>(x, M, out);
}

// Round 14
// 213.093 us; speedup vs baseline: 1.1265x; 1.1265x over previous
//
#include <hip/hip_runtime.h>
#include <math.h>

#define B_   16
#define C_   256
#define T_   8192
#define BINS 16
#define NFFT 30

typedef __attribute__((ext_vector_type(8))) _Float16 f16x8;
typedef __attribute__((ext_vector_type(2))) __fp16 fp16x2;
typedef __attribute__((ext_vector_type(4))) float f32x4;

typedef const __attribute__((address_space(1))) unsigned int ga_u32;
typedef __attribute__((address_space(3))) unsigned int ls_u32;

union f16pack { f16x8 v; fp16x2 p[4]; };

// ---------------- Kernel 1: k = Wk @ X  (fp16 out, float2 per thread) ----------------
__global__ __launch_bounds__(256) void k_kernel(const float* __restrict__ x,
                                                const float* __restrict__ Wk,
                                                _Float16* __restrict__ kk) {
  const int tc = blockIdx.x;   // 0..15
  const int b  = blockIdx.y;
  const int tid = threadIdx.x;
  const int t = tc*512 + tid*2;
  const float* xb = x + (size_t)b*C_*T_ + t;
  float2 acc[16];
#pragma unroll
  for (int cc = 0; cc < 16; ++cc) acc[cc] = make_float2(0.f, 0.f);
  for (int c4 = 0; c4 < 64; ++c4) {
    float2 xv[4];
#pragma unroll
    for (int j = 0; j < 4; ++j) xv[j] = *(const float2*)(xb + (size_t)(c4*4 + j)*T_);
#pragma unroll
    for (int cc = 0; cc < 16; ++cc) {
      const float4 w4 = *(const float4*)&Wk[cc*256 + c4*4];   // uniform -> s_load
      acc[cc].x += w4.x*xv[0].x + w4.y*xv[1].x + w4.z*xv[2].x + w4.w*xv[3].x;
      acc[cc].y += w4.x*xv[0].y + w4.y*xv[1].y + w4.z*xv[2].y + w4.w*xv[3].y;
    }
  }
#pragma unroll
  for (int cc = 0; cc < 16; ++cc) {
    fp16x2 hv;
    hv[0] = (__fp16)acc[cc].x;
    hv[1] = (__fp16)acc[cc].y;
    *(fp16x2*)&kk[((size_t)b*16 + cc)*T_ + t] = hv;
  }
}

// ---------------- Kernel 2: R partials = k @ X^T (MFMA, 32 K-splits) ----------------
static __device__ __forceinline__ void stage_panel(float* dstbase, const float* xb,
                                                   int koff, int tid) {
#pragma unroll
  for (int h = 0; h < 4; ++h) {
    const int idx = h*512 + tid;       // 0..2047 -> 2048 x 16B = 32 KB
    const int row = idx >> 3;          // 0..255
    const int ps  = idx & 7;           // physical 16B segment in row
    const int ls  = ps ^ (row & 7);    // logical segment (involution)
    const float* src = xb + (size_t)row*T_ + koff + ls*4;
    __builtin_amdgcn_global_load_lds((ga_u32*)src, (ls_u32*)(dstbase + idx*4), 16, 0, 0);
  }
}

__global__ __launch_bounds__(512, 4) void r_kernel(const float* __restrict__ x,
                                                   const _Float16* __restrict__ kk,
                                                   float* __restrict__ Rp) {
  const int ks = blockIdx.x;   // 0..31
  const int b  = blockIdx.y;
  constexpr int KCH = 256;

  __shared__ float P[2][256*32];

  const int tid  = threadIdx.x;
  const int lane = tid & 63;
  const int w    = tid >> 6;     // 0..7 -> ch-tile pair {2w, 2w+1}
  const int fr   = lane & 15;
  const int g    = lane >> 4;

  const float* xb = x + (size_t)b*C_*T_;
  const _Float16* kb = kk + (size_t)b*16*T_;
  const int t0 = ks * KCH;

  f32x4 acc[2];
  acc[0] = (f32x4){0.f,0.f,0.f,0.f};
  acc[1] = (f32x4){0.f,0.f,0.f,0.f};

  stage_panel(P[0], xb, t0, tid);
  __syncthreads();

  int cur = 0;
  for (int kt = 0; kt < KCH; kt += 32) {
    if (kt + 32 < KCH) stage_panel(P[cur ^ 1], xb, t0 + kt + 32, tid);

    const float* Pc = P[cur];
    const f16x8 ka = *(const f16x8*)&kb[(size_t)fr*T_ + t0 + kt + g*8];
#pragma unroll
    for (int nt = 0; nt < 2; ++nt) {
      const int r = (w*2 + nt)*16 + fr;   // ch row 0..255
      const float4 lo = *(const float4*)&Pc[r*32 + (((2*g+0) ^ (r&7))<<2)];
      const float4 hi = *(const float4*)&Pc[r*32 + (((2*g+1) ^ (r&7))<<2)];
      f16pack fb;
      fb.p[0] = __builtin_amdgcn_cvt_pkrtz(lo.x, lo.y);
      fb.p[1] = __builtin_amdgcn_cvt_pkrtz(lo.z, lo.w);
      fb.p[2] = __builtin_amdgcn_cvt_pkrtz(hi.x, hi.y);
      fb.p[3] = __builtin_amdgcn_cvt_pkrtz(hi.z, hi.w);
      acc[nt] = __builtin_amdgcn_mfma_f32_16x16x32_f16(ka, fb.v, acc[nt], 0, 0, 0);
    }
    __syncthreads();
    cur ^= 1;
  }

  float* rp = Rp + ((size_t)(ks*16 + b))*4096;
#pragma unroll
  for (int nt = 0; nt < 2; ++nt)
#pragma unroll
    for (int r = 0; r < 4; ++r) {
      const int cc = g*4 + r;               // C/D row = A-side m (cc)
      const int ch = (w*2 + nt)*16 + fr;    // C/D col = B-side n (ch)
      rp[cc*256 + ch] = acc[nt][r];
    }
}

// ---------------- Kernel 2b: parallel reduce of 32 Rp partials -> wkg ----------------
__global__ __launch_bounds__(256) void reduce_kernel(const float* __restrict__ Rp,
                                                     float* __restrict__ wkg) {
  const int idx = blockIdx.x*256 + threadIdx.x;   // 0..65535
  const int b   = idx >> 12;
  const int rem = idx & 4095;
  float s = 0.f;
#pragma unroll 8
  for (int p = 0; p < 32; ++p)
    s += Rp[((size_t)(p*16 + b))*4096 + rem];
  wkg[idx] = s;
}

// ---------------- Kernel 3: scores -> softmax -> M = P @ Wv (512 thr) ----------------
__global__ __launch_bounds__(512) void attn_b(const float* __restrict__ Wq,
                                              const float* __restrict__ Wv,
                                              const float* __restrict__ wkg,
                                              float* __restrict__ Mout) {
  const int b = blockIdx.x;
  const int tid = threadIdx.x;
  __shared__ float s1[16*256];
  __shared__ float s2[16*256];
  __shared__ float invs[16];

  for (int i = tid; i < 4096; i += 512) s1[i] = wkg[(size_t)b*4096 + i];
  __syncthreads();

  const int h   = tid >> 8;    // 0..1 (cc half)
  const int col = tid & 255;

  float sc[8];
#pragma unroll
  for (int i = 0; i < 8; ++i) sc[i] = 0.f;
  for (int c4 = 0; c4 < 64; ++c4) {
    const float4 wq4 = *(const float4*)&Wq[(size_t)col*256 + c4*4];
#pragma unroll
    for (int i = 0; i < 8; ++i) {
      const float4 p4 = *(const float4*)&s1[(h*8 + i)*256 + c4*4];
      sc[i] += p4.x*wq4.x + p4.y*wq4.y + p4.z*wq4.z + p4.w*wq4.w;
    }
  }
#pragma unroll
  for (int i = 0; i < 8; ++i) s2[(h*8 + i)*256 + col] = sc[i] * 0.0625f;
  __syncthreads();

  // softmax: 16 rows x 32 lanes (shfl stays within 32-lane half)
  {
    const int rr = tid >> 5, jj = tid & 31;
    float mx = -1e30f;
    for (int c = jj; c < 256; c += 32) mx = fmaxf(mx, s2[rr*256 + c]);
#pragma unroll
    for (int o = 1; o < 32; o <<= 1) mx = fmaxf(mx, __shfl_xor(mx, o, 64));
    float sm = 0.f;
    for (int c = jj; c < 256; c += 32) {
      const float e = __expf(s2[rr*256 + c] - mx);
      s2[rr*256 + c] = e;
      sm += e;
    }
#pragma unroll
    for (int o = 1; o < 32; o <<= 1) sm += __shfl_xor(sm, o, 64);
    if (jj == 0) invs[rr] = 1.f / sm;
  }
  __syncthreads();

  float mac[8];
#pragma unroll
  for (int i = 0; i < 8; ++i) mac[i] = 0.f;
  for (int c4 = 0; c4 < 64; ++c4) {
    float wv[4];
#pragma unroll
    for (int j = 0; j < 4; ++j) wv[j] = Wv[(size_t)(c4*4 + j)*256 + col];
#pragma unroll
    for (int i = 0; i < 8; ++i) {
      const float4 p4 = *(const float4*)&s2[(h*8 + i)*256 + c4*4];
      mac[i] += p4.x*wv[0] + p4.y*wv[1] + p4.z*wv[2] + p4.w*wv[3];
    }
  }
#pragma unroll
  for (int i = 0; i < 8; ++i)
    Mout[(size_t)b*4096 + (h*8 + i)*256 + col] = mac[i] * invs[h*8 + i];
}

// ---------------- Kernel 4: seq = M @ X  (256 blocks, float2) ----------------
__global__ __launch_bounds__(256) void outp_kernel(const float* __restrict__ x,
                                                   const float* __restrict__ M,
                                                   float* __restrict__ seq) {
  const int tc = blockIdx.x;   // 0..15
  const int b  = blockIdx.y;
  const int tid = threadIdx.x;
  const int t  = tc*512 + tid*2;
  const float* xb = x + (size_t)b*C_*T_ + t;
  const float* mb = M + (size_t)b*4096;
  float2 a[16];
#pragma unroll
  for (int cc = 0; cc < 16; ++cc) a[cc] = make_float2(0.f, 0.f);
  for (int ch = 0; ch < 64; ++ch) {
    float2 xv[4];
#pragma unroll
    for (int j = 0; j < 4; ++j)
      xv[j] = *(const float2*)(xb + (size_t)(ch*4 + j) * T_);
#pragma unroll
    for (int cc = 0; cc < 16; ++cc) {
      const float4 m4 = *(const float4*)(mb + cc*256 + ch*4);
      a[cc].x += m4.x*xv[0].x + m4.y*xv[1].x + m4.z*xv[2].x + m4.w*xv[3].x;
      a[cc].y += m4.x*xv[0].y + m4.y*xv[1].y + m4.z*xv[2].y + m4.w*xv[3].y;
    }
  }
#pragma unroll
  for (int cc = 0; cc < 16; ++cc)
    *(float2*)(seq + (size_t)(b*16 + cc)*T_ + t) = a[cc];
}

// ---------------- Kernel 5: windowed-DFT power spectrogram ----------------
__global__ __launch_bounds__(256) void spec_kernel(const float* __restrict__ seq,
                                                   float* __restrict__ out) {
  const int tcx = blockIdx.x;  // 0..31
  const int r   = blockIdx.y;  // 0..255
  const int tid = threadIdx.x;
  const int t0  = tcx * 256;

  __shared__ float smem[288];
  __shared__ float ctab[BINS*NFFT];
  __shared__ float stab[BINS*NFFT];

  const float* row = seq + (size_t)r * T_;
  for (int i = tid; i < 288; i += 256) {
    int gg = t0 - 15 + i;
    if (gg < 0) gg = -gg;
    if (gg > T_-1) gg = 2*(T_-1) - gg;
    smem[i] = row[gg];
  }
  for (int i = tid; i < BINS*NFFT; i += 256) {
    const int k = i / NFFT, n = i % NFFT;
    const float TWO_PI = 6.283185307179586f;
    const float wn = 0.5f - 0.5f * cosf(TWO_PI * (float)n / (float)NFFT);
    const float ang = TWO_PI * (float)(k * n) / (float)NFFT;
    ctab[i] = cosf(ang) * wn;
    stab[i] = sinf(ang) * wn;
  }
  __syncthreads();

  const int k   = tid >> 4;
  const int sub = tid & 15;
  float cr[NFFT], ci[NFFT];
#pragma unroll
  for (int n = 0; n < NFFT; ++n) { cr[n] = ctab[k*NFFT + n]; ci[n] = stab[k*NFFT + n]; }

  float* orow = out + (size_t)(r*BINS + k) * T_ + t0;
  const float inv_norm = 1.0f / 11.25f;

  for (int jj = 0; jj < 4; ++jj) {
    const int x0 = 4*sub + 64*jj;
    float smp[36];
#pragma unroll
    for (int q = 0; q < 9; ++q) {
      const float4 v = *(const float4*)&smem[x0 + 4*q];
      smp[4*q+0] = v.x; smp[4*q+1] = v.y; smp[4*q+2] = v.z; smp[4*q+3] = v.w;
    }
    float4 pw;
#pragma unroll
    for (int p = 0; p < 4; ++p) {
      float re = 0.f, im = 0.f;
#pragma unroll
      for (int n = 0; n < NFFT; ++n) {
        re += cr[n] * smp[p + n];
        im += ci[n] * smp[p + n];
      }
      ((float*)&pw)[p] = (re*re + im*im) * inv_norm;
    }
    *(float4*)(orow + x0) = pw;
  }
}

// ---------------- launch ----------------
extern "C" void kernel_launch(void* const* d_in, const int* in_sizes, int n_in,
                              void* d_out, int out_size, void* d_ws, size_t ws_size,
                              hipStream_t stream) {
  const float* x  = (const float*)d_in[0];
  const float* Wk = (const float*)d_in[1];
  const float* Wq = (const float*)d_in[2];
  const float* Wv = (const float*)d_in[3];
  float* out = (float*)d_out;
  float* ws  = (float*)d_ws;

  // float-slot layout (total ~5.4M floats = 21.5 MB):
  _Float16* kk = (_Float16*)ws;            // 16*16*8192 halfs = 1,048,576 slots
  float* Rp   = ws + 1048576;              // 32*16*16*256 = 2,097,152
  float* wkg  = Rp + 2097152;              // 65,536
  float* M    = wkg + 65536;               // 65,536
  float* seq  = M + 65536;                 // 2,097,152

  k_kernel<<<dim3(16, 16), 256, 0, stream>>>(x, Wk, kk);
  r_kernel<<<dim3(32, 16), 512, 0, stream>>>(x, kk, Rp);
  reduce_kernel<<<dim3(256), 256, 0, stream>>>(Rp, wkg);
  attn_b<<<dim3(16), 512, 0, stream>>>(Wq, Wv, wkg, M);
  outp_kernel<<<dim3(16, 16), 256, 0, stream>>>(x, M, seq);
  spec_kernel<<<dim3(32, 256), 256, 0, stream>>>(seq, out);
}